// Round 6
// baseline (48.478 us; speedup 1.0000x reference)
//
#include <hip/hip_runtime.h>
#include <math.h>

// DescGroupPoolandNorm (pool='shift', candidate='top1', norm='l2')
//   B=4, K=8192, CG=1024, G=8, C=128
//   s = argmax over g of desc[b,k, g]  (first channel group, first-wins)
//   out[b,k, c*8+j] = desc[b,k, c*8 + (j+s)%8] / (||desc[b,k,:]||_2 + 1e-6)
//   kpts passes through (fused, spread 128 B/block).
//
// Round-6: perfectly balanced grid. Exactly 2048 blocks = 8 blocks/CU on
// 256 CUs = 32 waves/CU (100% static occupancy, no tail round). Each block:
// 4 waves x RPW=4 rows (packed float4 accesses, 1024 B dense per instr).
// kpts (256 KB) is folded in as 128 B per block (first 32 lanes of wave 0)
// instead of 64 trailing copy-only blocks that unbalanced the grid.
//
// Roll math (packed layout): group of 8 floats spans an even/odd lane pair.
//   own  = lane's float4; other = __shfl_xor(own,1)
//   X = (s<4) ? own : other;  Y = the other one      // WAVE-UNIFORM select
//   result = window [s&3 .. (s&3)+3] of concat(X,Y)  // uniform switch
// (per-lane parity cancels out of the X/Y select: window start w=(s+4p)&7,
//  half h=(s>>2)^p, X=own iff p^h==0 iff s<4.)

#define ROWLEN 1024  // CG (floats per row)
#define RPW 4        // rows per wave

__device__ __forceinline__ float4 shfl_xor1(float4 v) {
    float4 r;
    r.x = __shfl_xor(v.x, 1);
    r.y = __shfl_xor(v.y, 1);
    r.z = __shfl_xor(v.z, 1);
    r.w = __shfl_xor(v.w, 1);
    return r;
}

// Window [U..U+3] of concat(X[0..3], Y[0..3]), scaled by inv.
template<int U>
__device__ __forceinline__ float4 window4(float4 X, float4 Y, float inv);
template<> __device__ __forceinline__ float4 window4<0>(float4 X, float4 Y, float inv) {
    return make_float4(X.x * inv, X.y * inv, X.z * inv, X.w * inv);
}
template<> __device__ __forceinline__ float4 window4<1>(float4 X, float4 Y, float inv) {
    return make_float4(X.y * inv, X.z * inv, X.w * inv, Y.x * inv);
}
template<> __device__ __forceinline__ float4 window4<2>(float4 X, float4 Y, float inv) {
    return make_float4(X.z * inv, X.w * inv, Y.x * inv, Y.y * inv);
}
template<> __device__ __forceinline__ float4 window4<3>(float4 X, float4 Y, float inv) {
    return make_float4(X.w * inv, Y.x * inv, Y.y * inv, Y.z * inv);
}

__device__ __forceinline__ void process_row_packed(
    const float4 v0, const float4 v1, const float4 v2, const float4 v3,
    float4* __restrict__ orow4, const int lane) {
    // ---- L2 norm (permutation-invariant): sum of squares + butterfly ----
    float ss = v0.x * v0.x + v0.y * v0.y + v0.z * v0.z + v0.w * v0.w
             + v1.x * v1.x + v1.y * v1.y + v1.z * v1.z + v1.w * v1.w
             + v2.x * v2.x + v2.y * v2.y + v2.z * v2.z + v2.w * v2.w
             + v3.x * v3.x + v3.y * v3.y + v3.z * v3.z + v3.w * v3.w;
#pragma unroll
    for (int off = 1; off < 64; off <<= 1) ss += __shfl_xor(ss, off);
    const float inv = 1.0f / (sqrtf(ss) + 1e-6f);

    // ---- argmax of row floats 0..7 (lane0: f0..3, lane1: f4..7) ----
    int bi_l = 0;
    float bv_l = v0.x;
    if (v0.y > bv_l) { bv_l = v0.y; bi_l = 1; }
    if (v0.z > bv_l) { bv_l = v0.z; bi_l = 2; }
    if (v0.w > bv_l) { bv_l = v0.w; bi_l = 3; }
    const float bv0 = __shfl(bv_l, 0);
    const float bv1 = __shfl(bv_l, 1);
    const int bi0 = __shfl(bi_l, 0);
    const int bi1 = __shfl(bi_l, 1);
    int s = (bv1 > bv0) ? (bi1 + 4) : bi0;  // first-wins: tie keeps lane0
    s = __builtin_amdgcn_readfirstlane(s);  // wave-uniform -> scalar branches

    // ---- partner halves ----
    const float4 o0 = shfl_xor1(v0);
    const float4 o1 = shfl_xor1(v1);
    const float4 o2 = shfl_xor1(v2);
    const float4 o3 = shfl_xor1(v3);

    // Wave-uniform X/Y select (parity cancels; see header comment).
    float4 X0, X1, X2, X3, Y0, Y1, Y2, Y3;
    if (s < 4) {
        X0 = v0; X1 = v1; X2 = v2; X3 = v3;
        Y0 = o0; Y1 = o1; Y2 = o2; Y3 = o3;
    } else {
        X0 = o0; X1 = o1; X2 = o2; X3 = o3;
        Y0 = v0; Y1 = v1; Y2 = v2; Y3 = v3;
    }

    float4 r0, r1, r2, r3;
    switch (s & 3) {  // uniform residual shift, compile-time indices
        case 0:
            r0 = window4<0>(X0, Y0, inv); r1 = window4<0>(X1, Y1, inv);
            r2 = window4<0>(X2, Y2, inv); r3 = window4<0>(X3, Y3, inv);
            break;
        case 1:
            r0 = window4<1>(X0, Y0, inv); r1 = window4<1>(X1, Y1, inv);
            r2 = window4<1>(X2, Y2, inv); r3 = window4<1>(X3, Y3, inv);
            break;
        case 2:
            r0 = window4<2>(X0, Y0, inv); r1 = window4<2>(X1, Y1, inv);
            r2 = window4<2>(X2, Y2, inv); r3 = window4<2>(X3, Y3, inv);
            break;
        default:
            r0 = window4<3>(X0, Y0, inv); r1 = window4<3>(X1, Y1, inv);
            r2 = window4<3>(X2, Y2, inv); r3 = window4<3>(X3, Y3, inv);
            break;
    }

    // Packed stores: 1024 B dense per instruction.
    orow4[lane] = r0;
    orow4[lane + 64] = r1;
    orow4[lane + 128] = r2;
    orow4[lane + 192] = r3;
}

__global__ __launch_bounds__(256) void REDFM_15676630630653_kernel(
    const float* __restrict__ desc, float* __restrict__ out,
    const float* __restrict__ kpts, float* __restrict__ kpts_out) {
    const int lane = threadIdx.x & 63;

    // Fold the 256 KB kpts pass-through in evenly: 128 B per block
    // (first 32 lanes of wave 0). 2048 blocks x 32 floats = 65536 floats.
    if (threadIdx.x < 32) {
        const int i = blockIdx.x * 32 + threadIdx.x;
        kpts_out[i] = kpts[i];
    }

    const int wid = (blockIdx.x * 256 + threadIdx.x) >> 6;  // global wave id
    const int r0 = wid * RPW;

    const float4* __restrict__ rowp = (const float4*)(desc + (size_t)r0 * ROWLEN);

    // Prologue: load row r0 (packed: each instr = 1024 B contiguous).
    float4 c0 = rowp[lane];
    float4 c1 = rowp[lane + 64];
    float4 c2 = rowp[lane + 128];
    float4 c3 = rowp[lane + 192];

#pragma unroll
    for (int i = 0; i < RPW; i++) {
        float4 n0, n1, n2, n3;
        if (i + 1 < RPW) {
            // Next row's loads issued BEFORE consuming current row: the
            // vmcnt wait for c* leaves n* in flight under compute+stores.
            const float4* np = rowp + (size_t)(i + 1) * (ROWLEN / 4);
            n0 = np[lane];
            n1 = np[lane + 64];
            n2 = np[lane + 128];
            n3 = np[lane + 192];
        }
        process_row_packed(c0, c1, c2, c3,
                           (float4*)(out + (size_t)(r0 + i) * ROWLEN), lane);
        if (i + 1 < RPW) { c0 = n0; c1 = n1; c2 = n2; c3 = n3; }
    }
}

extern "C" void kernel_launch(void* const* d_in, const int* in_sizes, int n_in,
                              void* d_out, int out_size, void* d_ws, size_t ws_size,
                              hipStream_t stream) {
    const float* kpts = (const float*)d_in[0];
    const float* desc = (const float*)d_in[1];
    float* out = (float*)d_out;

    const int kpts_elems = in_sizes[0];            // B*K*2 = 65536
    float* desc_out = out + kpts_elems;

    // rows = 32768 = 2048 blocks x 4 waves x RPW(4) rows. Exactly 8 blocks
    // per CU on 256 CUs -> no tail round, 100% static occupancy.
    const int descBlocks = 2048;
    REDFM_15676630630653_kernel<<<descBlocks, 256, 0, stream>>>(
        desc, desc_out, kpts, out);
}